// Round 17
// baseline (175.652 us; speedup 1.0000x reference)
//
#include <hip/hip_runtime.h>

#define N_NODES 50000
#define N_EDGES 800000
#define F_IN    512
#define HID     128
#define OUT_F   20
#define CAP     48           // max in-degree capacity (mean 16, 8 sigma headroom)

#define BM  32
#define GEMM_BLOCKS ((N_NODES + BM - 1) / BM)   // 1563 = 521*3
#define FB_BLOCKS   521
#define FAT_BLOCKS  (FB_BLOCKS * 4)             // 2084: bid&3==3 -> fillb, else gemm

typedef __bf16 bf16x8 __attribute__((ext_vector_type(8)));
typedef float  f32x4  __attribute__((ext_vector_type(4)));

// ---------------- prep: W1 -> frag-ready permuted bf16 + cursor init (fused) ----------

__global__ void k_prep(const float* __restrict__ W1, __bf16* __restrict__ w1p,
                       int* __restrict__ cursor) {
    int gidx = blockIdx.x * blockDim.x + threadIdx.x;
    if (gidx < F_IN * HID) {
        int k  = gidx >> 7;
        int cc = gidx & (HID - 1);
        int kk = k >> 5;
        int r  = k & 31;
        int g  = (r & 15) >> 2;
        int j  = (r & 3) + ((r >> 4) << 2);
        w1p[((((size_t)kk * 4 + g) * 128 + cc) << 3) + j] = (__bf16)W1[gidx];
    }
    if (gidx < N_NODES) cursor[gidx] = gidx * CAP;
}

// ---------------- FAT kernel: gemm1 (all-gload_lds pipeline) || fillb (atomic CSR) ----
// r16 bug was the B-frag ni-stride: 128 __bf16 ELEMENTS (16 cols x 8), not 128*8.
// Everything else unchanged: A and B both staged via global_load_lds (no in-loop
// regular VMEM -> counted vmcnt holds), BK=32, 3 LDS buffers, depth-2 prefetch,
// s_waitcnt vmcnt(6/3/0) + raw s_barrier x2/step.

__global__ __launch_bounds__(256) void k_fat(const float* __restrict__ x,
                                             const __bf16* __restrict__ w1p,
                                             __bf16* __restrict__ hb,
                                             const int* __restrict__ row,
                                             const int* __restrict__ col,
                                             const float* __restrict__ ew,
                                             int* __restrict__ cursor,
                                             uint2* __restrict__ packed) {
    __shared__ float  As[3][BM * 32];     // 4 KB per buffer
    __shared__ __bf16 Bs[3][4096];        // 8 KB per buffer (one 32-k frag block)
    const int tid = threadIdx.x;
    const int q   = blockIdx.x >> 2;
    const int r3  = blockIdx.x & 3;

    if (r3 == 3) {
        // ---------- fillb path: 4 edges/iter, 4 independent atomics in flight --------
        for (int v = q * 256 + tid; v < N_EDGES / 4; v += FB_BLOCKS * 256) {
            int4   c4 = ((const int4*)col)[v];
            int4   r4 = ((const int4*)row)[v];
            float4 w4 = ((const float4*)ew)[v];
            int p0 = atomicAdd(&cursor[c4.x], 1);
            int p1 = atomicAdd(&cursor[c4.y], 1);
            int p2 = atomicAdd(&cursor[c4.z], 1);
            int p3 = atomicAdd(&cursor[c4.w], 1);
            packed[p0] = make_uint2((unsigned)r4.x, __float_as_uint(w4.x));
            packed[p1] = make_uint2((unsigned)r4.y, __float_as_uint(w4.y));
            packed[p2] = make_uint2((unsigned)r4.z, __float_as_uint(w4.z));
            packed[p3] = make_uint2((unsigned)r4.w, __float_as_uint(w4.w));
        }
        return;
    }

    // ---------- gemm1 path ----------
    const int gemm_id = q * 3 + r3;       // 0..1562, each exactly once
    const int lane = tid & 63;
    const int wid  = tid >> 6;
    const int wm   = wid >> 1;            // row block of 16
    const int wn   = wid & 1;             // col block of 64
    const int r0   = gemm_id * BM;
    const int g    = lane >> 4;           // k-group 0..3
    const int l15  = lane & 15;

    f32x4 acc0 = {}, acc1 = {}, acc2 = {}, acc3 = {};

    // stage one 32-k tile: A 256 chunks (1/thread) + B 512 chunks (2/thread), all
    // global_load_lds, 16B each. 3 loads/thread/stage.
    auto stage = [&](int buf, int t) {
        {   // A: chunk c = wid*64+lane; row = c>>3, slot s = c&7; source-swizzled
            int c    = (wid << 6) + lane;
            int rowc = c >> 3;
            int s    = c & 7;
            int gr   = r0 + rowc;
            if (gr >= N_NODES) gr = N_NODES - 1;
            const float* src = x + (size_t)gr * F_IN + (t << 5) + ((s ^ (rowc & 7)) << 2);
            __builtin_amdgcn_global_load_lds(
                (const __attribute__((address_space(1))) void*)src,
                (__attribute__((address_space(3))) void*)(&As[buf][(size_t)c * 4]),
                16, 0, 0);
        }
#pragma unroll
        for (int i = 0; i < 2; ++i) {   // B: linear copy of 8 KB frag block
            int c = (wid << 7) + (i << 6) + lane;
            const __bf16* srcb = w1p + (size_t)t * 4096 + (size_t)c * 8;
            __builtin_amdgcn_global_load_lds(
                (const __attribute__((address_space(1))) void*)srcb,
                (__attribute__((address_space(3))) void*)(&Bs[buf][(size_t)c * 8]),
                16, 0, 0);
        }
    };

    const int rowm  = wm * 16 + l15;
    const int rbase = rowm * 32;
    const int rx    = rowm & 7;
    const int bbase = (wn * 64 + l15) * 8;   // + g*1024 + ni*128

    stage(0, 0);
    stage(1, 1);
    asm volatile("s_waitcnt vmcnt(3)" ::: "memory");   // stage(0) complete
    __builtin_amdgcn_s_barrier();

#pragma unroll
    for (int t = 0; t < 16; ++t) {
        const int buf = t % 3;
        if (t < 14) stage((t + 2) % 3, t + 2);
        if (t < 14)      asm volatile("s_waitcnt vmcnt(6)" ::: "memory");
        else if (t == 14) asm volatile("s_waitcnt vmcnt(3)" ::: "memory");
        else              asm volatile("s_waitcnt vmcnt(0)" ::: "memory");
        __builtin_amdgcn_s_barrier();      // all waves' stage(t) landed in LDS

        // A frag: two swizzled b128 reads, cvt at consume
        f32x4 lo = *(const f32x4*)&As[buf][rbase + ((g ^ rx) << 2)];
        f32x4 hi = *(const f32x4*)&As[buf][rbase + (((g + 4) ^ rx) << 2)];
        union { __bf16 h[8]; bf16x8 v; } u;
        u.h[0] = (__bf16)lo[0]; u.h[1] = (__bf16)lo[1];
        u.h[2] = (__bf16)lo[2]; u.h[3] = (__bf16)lo[3];
        u.h[4] = (__bf16)hi[0]; u.h[5] = (__bf16)hi[1];
        u.h[6] = (__bf16)hi[2]; u.h[7] = (__bf16)hi[3];
        // B frags from LDS: ni-stride = 128 __bf16 elements (16 cols x 8)
        const __bf16* bp = &Bs[buf][g * 1024 + bbase];
        bf16x8 b0 = *(const bf16x8*)(bp);
        bf16x8 b1 = *(const bf16x8*)(bp + 128);
        bf16x8 b2 = *(const bf16x8*)(bp + 256);
        bf16x8 b3 = *(const bf16x8*)(bp + 384);
        acc0 = __builtin_amdgcn_mfma_f32_16x16x32_bf16(u.v, b0, acc0, 0, 0, 0);
        acc1 = __builtin_amdgcn_mfma_f32_16x16x32_bf16(u.v, b1, acc1, 0, 0, 0);
        acc2 = __builtin_amdgcn_mfma_f32_16x16x32_bf16(u.v, b2, acc2, 0, 0, 0);
        acc3 = __builtin_amdgcn_mfma_f32_16x16x32_bf16(u.v, b3, acc3, 0, 0, 0);

        __builtin_amdgcn_s_barrier();      // buf reusable: all waves done reading
    }

    // epilogue: C/D col=lane&15, row=(lane>>4)*4+reg
    const int rb = r0 + wm * 16 + (g << 2);
#pragma unroll
    for (int rr = 0; rr < 4; ++rr) {
        int gr = rb + rr;
        if (gr < N_NODES) {
            __bf16* ho = hb + (size_t)gr * HID + wn * 64 + l15;
            ho[0]  = (__bf16)acc0[rr];
            ho[16] = (__bf16)acc1[rr];
            ho[32] = (__bf16)acc2[rr];
            ho[48] = (__bf16)acc3[rr];
        }
    }
}

// ---------------- deg/dinv from buckets (sequential, no atomics) ----------------

__global__ void k_degdinv(const int* __restrict__ cursor, const uint2* __restrict__ packed,
                          int* __restrict__ cnt, float* __restrict__ dinv) {
    int i = blockIdx.x * blockDim.x + threadIdx.x;
    if (i < N_NODES) {
        int n = cursor[i] - i * CAP;
        cnt[i] = n;
        const uint2* seg = packed + (size_t)i * CAP;
        float d = 1.0f;
        for (int k = 0; k < n; ++k) d += __uint_as_float(seg[k].y);
        dinv[i] = rsqrtf(d);   // d >= 1 always
    }
}

// ---------------- fused agg1 + relu + gemm2: h2[c] = relu(agg1(c)+b1) @ W2 ------------

__device__ inline float blo(unsigned v) { union { unsigned u; float f; } c; c.u = v << 16; return c.f; }
__device__ inline float bhi(unsigned v) { union { unsigned u; float f; } c; c.u = v & 0xffff0000u; return c.f; }

__global__ __launch_bounds__(128) void k_agg1g2(uint2* __restrict__ packed,
                                                const int* __restrict__ cnt,
                                                const __bf16* __restrict__ hb,
                                                const float* __restrict__ dinv,
                                                const float* __restrict__ b1,
                                                const float* __restrict__ W2,
                                                float* __restrict__ h2) {
    __shared__ int   sr[2][64];
    __shared__ float sn[2][64];
    __shared__ float sh1[2][128];
    const int w    = threadIdx.x >> 6;
    const int lane = threadIdx.x & 63;
    const int c    = blockIdx.x * 2 + w;
    const unsigned* hbu = (const unsigned*)hb;

    float dic = dinv[c];
    unsigned sv = hbu[((size_t)c << 6) + lane];
    float a0 = dic * dic * blo(sv);
    float a1 = dic * dic * bhi(sv);
    int n = cnt[c];
    uint2* seg = packed + (size_t)c * CAP;
    for (int base = 0; base < n; base += 64) {
        int m = n - base; if (m > 64) m = 64;
        if (lane < m) {                       // wave-synchronous, no barrier
            uint2 pv = seg[base + lane];
            float nm = __uint_as_float(pv.y) * dinv[pv.x] * dic;
            sr[w][lane] = (int)pv.x;
            sn[w][lane] = nm;
            seg[base + lane] = make_uint2(pv.x, __float_as_uint(nm));  // norm write-back
        }
        for (int t = 0; t < m; ++t) {
            float nm = sn[w][t];
            unsigned v = hbu[((size_t)sr[w][t] << 6) + lane];
            a0 = fmaf(nm, blo(v), a0);
            a1 = fmaf(nm, bhi(v), a1);
        }
    }
    float2 bb = *(const float2*)(b1 + 2 * lane);
    a0 += bb.x; a1 += bb.y;
    sh1[w][2 * lane]     = a0 > 0.f ? a0 : 0.f;
    sh1[w][2 * lane + 1] = a1 > 0.f ? a1 : 0.f;

    // h2[c][j] = sum_k h1[k] * W2[k][j], 3-way k-split over lanes 0-59
    const int part = lane / 20;               // 0..3 (60-63 idle)
    const int j    = lane - part * 20;
    float s = 0.f;
    if (part < 3) {
        const int kbeg = part * 43;
        const int kend = (part == 2) ? 128 : kbeg + 43;
#pragma unroll 4
        for (int k = kbeg; k < kend; ++k)
            s = fmaf(sh1[w][k], W2[k * OUT_F + j], s);
    }
    float s1 = __shfl(s, lane + 20);
    float s2 = __shfl(s, lane + 40);
    if (lane < 20) h2[(size_t)c * OUT_F + lane] = s + s1 + s2;
}

// ---------------- layer 2 aggregation: norm precomputed in packed[].y ----------------

__global__ __launch_bounds__(256) void k_agg2(const uint2* __restrict__ packed,
                                              const int* __restrict__ cnt,
                                              const float* __restrict__ h2,
                                              const float* __restrict__ dinv,
                                              const float* __restrict__ b2,
                                              float* __restrict__ out) {
    int g = blockIdx.x * blockDim.x + threadIdx.x;
    int c = g >> 5;
    int j = g & 31;
    if (c >= N_NODES || j >= OUT_F) return;
    float dic = dinv[c];
    float acc = dic * dic * h2[(size_t)c * OUT_F + j] + b2[j];
    int n = cnt[c];
    const uint2* seg = packed + (size_t)c * CAP;
    for (int k = 0; k < n; ++k) {
        uint2 pv = seg[k];                    // broadcast across lanes
        acc = fmaf(__uint_as_float(pv.y), h2[(size_t)pv.x * OUT_F + j], acc);
    }
    out[(size_t)c * OUT_F + j] = acc;
}

// ---------------- launch ----------------

extern "C" void kernel_launch(void* const* d_in, const int* in_sizes, int n_in,
                              void* d_out, int out_size, void* d_ws, size_t ws_size,
                              hipStream_t stream) {
    const float* x  = (const float*)d_in[0];
    const int*   ei = (const int*)d_in[1];       // [2][E]
    const float* ew = (const float*)d_in[2];
    const float* W1 = (const float*)d_in[3];
    const float* b1 = (const float*)d_in[4];
    const float* W2 = (const float*)d_in[5];
    const float* b2 = (const float*)d_in[6];
    float* out = (float*)d_out;

    const int* row = ei;
    const int* col = ei + N_EDGES;

    char* p = (char*)d_ws;
    float* dinv    = (float*)p;    p += (size_t)N_NODES * 4;
    float* h2      = (float*)p;    p += (size_t)N_NODES * OUT_F * 4;
    __bf16* hb     = (__bf16*)p;   p += (size_t)N_NODES * HID * 2;
    __bf16* w1p    = (__bf16*)p;   p += (size_t)F_IN * HID * 2;
    int* cursor    = (int*)p;      p += (size_t)N_NODES * 4;
    int* cnt       = (int*)p;      p += (size_t)N_NODES * 4;
    uint2* packed  = (uint2*)p;    p += (size_t)N_NODES * CAP * 8;

    // prep (W1 permute + cursor init)
    k_prep<<<(F_IN * HID + 255) / 256, 256, 0, stream>>>(W1, w1p, cursor);

    // fat kernel: gemm1 (all-gload_lds pipeline) || fillb (atomic bucket CSR)
    k_fat<<<FAT_BLOCKS, 256, 0, stream>>>(x, w1p, hb, row, col, ew, cursor, packed);

    k_degdinv<<<(N_NODES + 255) / 256, 256, 0, stream>>>(cursor, packed, cnt, dinv);

    // fused: agg1 + bias + relu + (h1 @ W2) -> h2 ; also writes norm back into packed
    k_agg1g2<<<N_NODES / 2, 128, 0, stream>>>(packed, cnt, hb, dinv, b1, W2, h2);

    // layer 2 aggregation
    k_agg2<<<(N_NODES * 32 + 255) / 256, 256, 0, stream>>>(packed, cnt, h2, dinv, b2, out);
}

// Round 18
// 162.756 us; speedup vs baseline: 1.0792x; 1.0792x over previous
//
#include <hip/hip_runtime.h>

#define N_NODES 50000
#define N_EDGES 800000
#define F_IN    512
#define HID     128
#define OUT_F   20
#define CAP     48           // max in-degree capacity (mean 16, 8 sigma headroom)

#define BM  32
#define GEMM_BLOCKS ((N_NODES + BM - 1) / BM)   // 1563 = 521*3
#define FB_BLOCKS   521
#define FAT_BLOCKS  (FB_BLOCKS * 4)             // 2084: bid&3==3 -> fillb, else gemm

typedef __bf16 bf16x8 __attribute__((ext_vector_type(8)));
typedef float  f32x4  __attribute__((ext_vector_type(4)));

// ---------------- prep: W1 -> frag-ready permuted bf16 + cursor init (fused) ----------

__global__ void k_prep(const float* __restrict__ W1, __bf16* __restrict__ w1p,
                       int* __restrict__ cursor) {
    int gidx = blockIdx.x * blockDim.x + threadIdx.x;
    if (gidx < F_IN * HID) {
        int k  = gidx >> 7;
        int cc = gidx & (HID - 1);
        int kk = k >> 5;
        int r  = k & 31;
        int g  = (r & 15) >> 2;
        int j  = (r & 3) + ((r >> 4) << 2);
        w1p[((((size_t)kk * 4 + g) * 128 + cc) << 3) + j] = (__bf16)W1[gidx];
    }
    if (gidx < N_NODES) cursor[gidx] = gidx * CAP;
}

// ---------------- FAT kernel: gemm1 (r14-best config) || fillb (atomic CSR) ----------
// r17 falsified the vmcnt-drain theory (B-via-LDS: no gain, -16% occ). Reverting the
// gemm path to the measured-best r14 structure: BK=64, 2 LDS buffers (16 KB total),
// __syncthreads per tile, B frags as regular VMEM loads from L2-hot w1p.

__global__ __launch_bounds__(256) void k_fat(const float* __restrict__ x,
                                             const __bf16* __restrict__ w1p,
                                             __bf16* __restrict__ hb,
                                             const int* __restrict__ row,
                                             const int* __restrict__ col,
                                             const float* __restrict__ ew,
                                             int* __restrict__ cursor,
                                             uint2* __restrict__ packed) {
    __shared__ float As[2][BM * 64];      // 8 KB per buffer (gemm path only)
    const int tid = threadIdx.x;
    const int q   = blockIdx.x >> 2;
    const int r3  = blockIdx.x & 3;

    if (r3 == 3) {
        // ---------- fillb path: 4 edges/iter, 4 independent atomics in flight --------
        for (int v = q * 256 + tid; v < N_EDGES / 4; v += FB_BLOCKS * 256) {
            int4   c4 = ((const int4*)col)[v];
            int4   r4 = ((const int4*)row)[v];
            float4 w4 = ((const float4*)ew)[v];
            int p0 = atomicAdd(&cursor[c4.x], 1);
            int p1 = atomicAdd(&cursor[c4.y], 1);
            int p2 = atomicAdd(&cursor[c4.z], 1);
            int p3 = atomicAdd(&cursor[c4.w], 1);
            packed[p0] = make_uint2((unsigned)r4.x, __float_as_uint(w4.x));
            packed[p1] = make_uint2((unsigned)r4.y, __float_as_uint(w4.y));
            packed[p2] = make_uint2((unsigned)r4.z, __float_as_uint(w4.z));
            packed[p3] = make_uint2((unsigned)r4.w, __float_as_uint(w4.w));
        }
        return;
    }

    // ---------- gemm1 path (r14 structure) ----------
    const int gemm_id = q * 3 + r3;       // 0..1562, each exactly once
    const int lane = tid & 63;
    const int wid  = tid >> 6;
    const int wm   = wid >> 1;            // row block of 16
    const int wn   = wid & 1;             // col block of 64
    const int r0   = gemm_id * BM;
    const int g    = lane >> 4;           // k-group 0..3
    const int l15  = lane & 15;

    const __bf16* pb = w1p + (((size_t)g * 128) + wn * 64 + l15) * 8;  // + kkg*4096

    f32x4 acc0 = {}, acc1 = {}, acc2 = {}, acc3 = {};

    auto stage = [&](int buf, int k0) {
#pragma unroll
        for (int i = 0; i < 2; ++i) {
            int cb = wid * 64 + i * 256;          // wave-uniform chunk base
            int c  = cb + lane;                    // chunk id 0..511
            int rowc = c >> 4;                     // row 0..31 (16 chunks/row)
            int s    = c & 15;                     // 16B slot in row
            int gr = r0 + rowc;
            if (gr >= N_NODES) gr = N_NODES - 1;   // clamp (stores guarded later)
            const float* src = x + (size_t)gr * F_IN + k0 + ((s ^ (rowc & 7)) << 2);
            __builtin_amdgcn_global_load_lds(
                (const __attribute__((address_space(1))) void*)src,
                (__attribute__((address_space(3))) void*)(&As[buf][(size_t)cb * 4]),
                16, 0, 0);
        }
    };

    const int rowm = wm * 16 + l15;
    const int rbase = rowm * 64;
    const int rx = rowm & 7;

    stage(0, 0);
    __syncthreads();                      // drains vmcnt: tile 0 ready

#pragma unroll
    for (int t = 0; t < 8; ++t) {
        const int buf = t & 1;
        if (t < 7) stage(buf ^ 1, (t + 1) * 64);    // loads in flight across compute
#pragma unroll
        for (int kk = 0; kk < 2; ++kk) {
            int slo = ((kk * 8 + g)     ^ rx) << 2;
            int shi = ((kk * 8 + g + 4) ^ rx) << 2;
            f32x4 lo = *(const f32x4*)&As[buf][rbase + slo];
            f32x4 hi = *(const f32x4*)&As[buf][rbase + shi];
            union { __bf16 h[8]; bf16x8 v; } u;
            u.h[0] = (__bf16)lo[0]; u.h[1] = (__bf16)lo[1];
            u.h[2] = (__bf16)lo[2]; u.h[3] = (__bf16)lo[3];
            u.h[4] = (__bf16)hi[0]; u.h[5] = (__bf16)hi[1];
            u.h[6] = (__bf16)hi[2]; u.h[7] = (__bf16)hi[3];
            const __bf16* bp = pb + (size_t)(t * 2 + kk) * 4096;
            bf16x8 b0 = *(const bf16x8*)(bp);
            bf16x8 b1 = *(const bf16x8*)(bp + 128);
            bf16x8 b2 = *(const bf16x8*)(bp + 256);
            bf16x8 b3 = *(const bf16x8*)(bp + 384);
            acc0 = __builtin_amdgcn_mfma_f32_16x16x32_bf16(u.v, b0, acc0, 0, 0, 0);
            acc1 = __builtin_amdgcn_mfma_f32_16x16x32_bf16(u.v, b1, acc1, 0, 0, 0);
            acc2 = __builtin_amdgcn_mfma_f32_16x16x32_bf16(u.v, b2, acc2, 0, 0, 0);
            acc3 = __builtin_amdgcn_mfma_f32_16x16x32_bf16(u.v, b3, acc3, 0, 0, 0);
        }
        __syncthreads();
    }

    const int rb = r0 + wm * 16 + (g << 2);
#pragma unroll
    for (int rr = 0; rr < 4; ++rr) {
        int gr = rb + rr;
        if (gr < N_NODES) {
            __bf16* ho = hb + (size_t)gr * HID + wn * 64 + l15;
            ho[0]  = (__bf16)acc0[rr];
            ho[16] = (__bf16)acc1[rr];
            ho[32] = (__bf16)acc2[rr];
            ho[48] = (__bf16)acc3[rr];
        }
    }
}

// ---------------- deg/dinv from buckets (sequential, no atomics) ----------------

__global__ void k_degdinv(const int* __restrict__ cursor, const uint2* __restrict__ packed,
                          int* __restrict__ cnt, float* __restrict__ dinv) {
    int i = blockIdx.x * blockDim.x + threadIdx.x;
    if (i < N_NODES) {
        int n = cursor[i] - i * CAP;
        cnt[i] = n;
        const uint2* seg = packed + (size_t)i * CAP;
        float d = 1.0f;
        for (int k = 0; k < n; ++k) d += __uint_as_float(seg[k].y);
        dinv[i] = rsqrtf(d);   // d >= 1 always
    }
}

// ---------------- fused agg1 + relu + gemm2: h2[c] = relu(agg1(c)+b1) @ W2 ------------

__device__ inline float blo(unsigned v) { union { unsigned u; float f; } c; c.u = v << 16; return c.f; }
__device__ inline float bhi(unsigned v) { union { unsigned u; float f; } c; c.u = v & 0xffff0000u; return c.f; }

__global__ __launch_bounds__(128) void k_agg1g2(uint2* __restrict__ packed,
                                                const int* __restrict__ cnt,
                                                const __bf16* __restrict__ hb,
                                                const float* __restrict__ dinv,
                                                const float* __restrict__ b1,
                                                const float* __restrict__ W2,
                                                float* __restrict__ h2) {
    __shared__ int   sr[2][64];
    __shared__ float sn[2][64];
    __shared__ float sh1[2][128];
    const int w    = threadIdx.x >> 6;
    const int lane = threadIdx.x & 63;
    const int c    = blockIdx.x * 2 + w;
    const unsigned* hbu = (const unsigned*)hb;

    float dic = dinv[c];
    unsigned sv = hbu[((size_t)c << 6) + lane];
    float a0 = dic * dic * blo(sv);
    float a1 = dic * dic * bhi(sv);
    int n = cnt[c];
    uint2* seg = packed + (size_t)c * CAP;
    for (int base = 0; base < n; base += 64) {
        int m = n - base; if (m > 64) m = 64;
        if (lane < m) {                       // wave-synchronous, no barrier
            uint2 pv = seg[base + lane];
            float nm = __uint_as_float(pv.y) * dinv[pv.x] * dic;
            sr[w][lane] = (int)pv.x;
            sn[w][lane] = nm;
            seg[base + lane] = make_uint2(pv.x, __float_as_uint(nm));  // norm write-back
        }
        for (int t = 0; t < m; ++t) {
            float nm = sn[w][t];
            unsigned v = hbu[((size_t)sr[w][t] << 6) + lane];
            a0 = fmaf(nm, blo(v), a0);
            a1 = fmaf(nm, bhi(v), a1);
        }
    }
    float2 bb = *(const float2*)(b1 + 2 * lane);
    a0 += bb.x; a1 += bb.y;
    sh1[w][2 * lane]     = a0 > 0.f ? a0 : 0.f;
    sh1[w][2 * lane + 1] = a1 > 0.f ? a1 : 0.f;

    // h2[c][j] = sum_k h1[k] * W2[k][j], 3-way k-split over lanes 0-59
    const int part = lane / 20;               // 0..3 (60-63 idle)
    const int j    = lane - part * 20;
    float s = 0.f;
    if (part < 3) {
        const int kbeg = part * 43;
        const int kend = (part == 2) ? 128 : kbeg + 43;
#pragma unroll 4
        for (int k = kbeg; k < kend; ++k)
            s = fmaf(sh1[w][k], W2[k * OUT_F + j], s);
    }
    float s1 = __shfl(s, lane + 20);
    float s2 = __shfl(s, lane + 40);
    if (lane < 20) h2[(size_t)c * OUT_F + lane] = s + s1 + s2;
}

// ---------------- layer 2 aggregation: 100% lane use, norm in packed[].y --------------

__global__ __launch_bounds__(256) void k_agg2(const uint2* __restrict__ packed,
                                              const int* __restrict__ cnt,
                                              const float* __restrict__ h2,
                                              const float* __restrict__ dinv,
                                              const float* __restrict__ b2,
                                              float* __restrict__ out) {
    int g = blockIdx.x * blockDim.x + threadIdx.x;
    if (g >= N_NODES * OUT_F) return;
    int c = g / OUT_F;                        // magic-mul div
    int j = g - c * OUT_F;
    float dic = dinv[c];
    float acc = dic * dic * h2[g] + b2[j];
    int n = cnt[c];
    const uint2* seg = packed + (size_t)c * CAP;
    for (int k = 0; k < n; ++k) {
        uint2 pv = seg[k];                    // same-address lanes broadcast in HW
        acc = fmaf(__uint_as_float(pv.y), h2[(size_t)pv.x * OUT_F + j], acc);
    }
    out[g] = acc;                             // fully coalesced
}

// ---------------- launch ----------------

extern "C" void kernel_launch(void* const* d_in, const int* in_sizes, int n_in,
                              void* d_out, int out_size, void* d_ws, size_t ws_size,
                              hipStream_t stream) {
    const float* x  = (const float*)d_in[0];
    const int*   ei = (const int*)d_in[1];       // [2][E]
    const float* ew = (const float*)d_in[2];
    const float* W1 = (const float*)d_in[3];
    const float* b1 = (const float*)d_in[4];
    const float* W2 = (const float*)d_in[5];
    const float* b2 = (const float*)d_in[6];
    float* out = (float*)d_out;

    const int* row = ei;
    const int* col = ei + N_EDGES;

    char* p = (char*)d_ws;
    float* dinv    = (float*)p;    p += (size_t)N_NODES * 4;
    float* h2      = (float*)p;    p += (size_t)N_NODES * OUT_F * 4;
    __bf16* hb     = (__bf16*)p;   p += (size_t)N_NODES * HID * 2;
    __bf16* w1p    = (__bf16*)p;   p += (size_t)F_IN * HID * 2;
    int* cursor    = (int*)p;      p += (size_t)N_NODES * 4;
    int* cnt       = (int*)p;      p += (size_t)N_NODES * 4;
    uint2* packed  = (uint2*)p;    p += (size_t)N_NODES * CAP * 8;

    // prep (W1 permute + cursor init)
    k_prep<<<(F_IN * HID + 255) / 256, 256, 0, stream>>>(W1, w1p, cursor);

    // fat kernel: gemm1 (r14-best LDS pipeline) || fillb (atomic bucket CSR)
    k_fat<<<FAT_BLOCKS, 256, 0, stream>>>(x, w1p, hb, row, col, ew, cursor, packed);

    k_degdinv<<<(N_NODES + 255) / 256, 256, 0, stream>>>(cursor, packed, cnt, dinv);

    // fused: agg1 + bias + relu + (h1 @ W2) -> h2 ; also writes norm back into packed
    k_agg1g2<<<N_NODES / 2, 128, 0, stream>>>(packed, cnt, hb, dinv, b1, W2, h2);

    // layer 2 aggregation
    k_agg2<<<(N_NODES * OUT_F + 255) / 256, 256, 0, stream>>>(packed, cnt, h2, dinv, b2, out);
}